// Round 6
// baseline (411.126 us; speedup 1.0000x reference)
//
#include <hip/hip_runtime.h>
#include <math.h>

#define N_NODES 50000
#define E_RAW   800000
#define E_TOT   850000
#define NEG_SLOPE 0.2f
#define NBC 196   // scan blocks = ceil(50000/256)

typedef __attribute__((ext_vector_type(8))) short short8;
typedef __attribute__((ext_vector_type(4))) float f32x4;

__device__ __forceinline__ float lrelu(float v) {
    return v >= 0.f ? v : NEG_SLOPE * v;
}
__device__ __forceinline__ unsigned short f2bf(float f) {
    union { float f; unsigned u; } v; v.f = f;
    unsigned r = v.u + 0x7FFF + ((v.u >> 16) & 1);
    return (unsigned short)(r >> 16);
}
__device__ __forceinline__ float bf2f(unsigned short h) {
    union { unsigned u; float f; } v; v.u = ((unsigned)h) << 16;
    return v.f;
}

// ---------------------------------------------------------------------------
// CSR build: histogram -> coalesced 3-phase scan -> scatter.
// ---------------------------------------------------------------------------
__global__ __launch_bounds__(256) void k_hist(
    const int* __restrict__ dst, int* __restrict__ counts)
{
    int e = blockIdx.x * 256 + threadIdx.x;
    if (e >= E_TOT) return;
    int d = (e < E_RAW) ? dst[e] : e - E_RAW;
    atomicAdd(&counts[d], 1);
}

__global__ __launch_bounds__(256) void k_scan1(
    const int* __restrict__ counts, int* __restrict__ off, int* __restrict__ bsum)
{
    __shared__ int sh[256];
    int t = threadIdx.x, i = blockIdx.x * 256 + t;
    int c = (i < N_NODES) ? counts[i] : 0;
    sh[t] = c; __syncthreads();
    for (int ofs = 1; ofs < 256; ofs <<= 1) {
        int v = (t >= ofs) ? sh[t - ofs] : 0;
        __syncthreads(); sh[t] += v; __syncthreads();
    }
    if (i < N_NODES) off[i] = sh[t] - c;
    if (t == 255) bsum[blockIdx.x] = sh[255];
}

__global__ __launch_bounds__(256) void k_scan2(int* __restrict__ bsum)
{
    __shared__ int sh[256];
    int t = threadIdx.x;
    int c = (t < NBC) ? bsum[t] : 0;
    sh[t] = c; __syncthreads();
    for (int ofs = 1; ofs < 256; ofs <<= 1) {
        int v = (t >= ofs) ? sh[t - ofs] : 0;
        __syncthreads(); sh[t] += v; __syncthreads();
    }
    if (t < NBC) bsum[t] = sh[t] - c;
}

__global__ __launch_bounds__(256) void k_scan3(
    int* __restrict__ off, const int* __restrict__ bsum)
{
    int i = blockIdx.x * 256 + threadIdx.x;
    if (i < N_NODES) off[i] += bsum[blockIdx.x];
    if (i == 0) off[N_NODES] = E_TOT;
}

__global__ __launch_bounds__(256) void k_scatter(
    const int* __restrict__ src, const int* __restrict__ dst,
    const int* __restrict__ off, int* __restrict__ cursor,
    int* __restrict__ esrc)
{
    int e = blockIdx.x * 256 + threadIdx.x;
    if (e >= E_TOT) return;
    int s, d;
    if (e < E_RAW) { s = src[e]; d = dst[e]; } else { s = e - E_RAW; d = s; }
    int pos = off[d] + atomicAdd(&cursor[d], 1);
    esrc[pos] = s;
}

// ---------------------------------------------------------------------------
// Weight prep into MFMA B-fragment order (bf16), plain k axis:
// Wf[(nbg*8+kb)*64+lane][j] = B[k=kb*32+(lane>>4)*8+j][col=nbg*16+(lane&15)]
// ---------------------------------------------------------------------------
__global__ __launch_bounds__(256) void k_prepw1(
    const float* __restrict__ W1, unsigned short* __restrict__ Wf1)
{
    int idx = blockIdx.x * 256 + threadIdx.x;       // 0..8191
    int lane = idx & 63, kb = (idx >> 6) & 7, nb = idx >> 9;
    int c = nb * 16 + (lane & 15);
    int k0 = kb * 32 + ((lane >> 4) & 3) * 8;
    short8 pk;
#pragma unroll
    for (int j = 0; j < 8; ++j)
        pk[j] = (short)f2bf(W1[(k0 + j) * 256 + c]);
    *(short8*)&Wf1[idx * 8] = pk;
}

__global__ __launch_bounds__(256) void k_prepw2(
    const float* __restrict__ W2, unsigned short* __restrict__ Wf2)
{
    int idx = blockIdx.x * 256 + threadIdx.x;       // 0..2047
    int lane = idx & 63, kb = (idx >> 6) & 7, nb = idx >> 9;
    int c = nb * 16 + (lane & 15);
    int k0 = kb * 32 + ((lane >> 4) & 3) * 8;
    short8 pk;
#pragma unroll
    for (int j = 0; j < 8; ++j)
        pk[j] = (short)f2bf(W2[(k0 + j) * 64 + c]);
    *(short8*)&Wf2[idx * 8] = pk;
}

// ---------------------------------------------------------------------------
// GEMM1: h1 = x @ W1, MFMA 16x16x32. 3125 blocks x 4 waves, 16 rows/block,
// wave w = head w (nb w*4..w*4+3). Register double-buffer of A and B.
// h1b stored PLAIN (h1b[n*256+col]); fused att-dot epilogue.
// ---------------------------------------------------------------------------
__global__ __launch_bounds__(256) void k_gemm1(
    const float* __restrict__ x, const unsigned short* __restrict__ Wf1,
    const float* __restrict__ att_src, const float* __restrict__ att_dst,
    unsigned short* __restrict__ h1b, float* __restrict__ as1, float* __restrict__ ad1)
{
    const int t = threadIdx.x;
    const int lane = t & 63;
    const int w = t >> 6;                           // wave = head = nb group
    const int rbase = blockIdx.x * 16;
    const int q  = lane & 15;
    const int kg = lane >> 4;
    const int rowA = rbase + q;

    f32x4 acc[4];
#pragma unroll
    for (int nb = 0; nb < 4; ++nb) acc[nb] = (f32x4){0.f, 0.f, 0.f, 0.f};

    short8 b[2][4];
    float4 a0, a1, a0n, a1n;
    {
        const float* ap = &x[rowA * 256 + kg * 8];
        a0 = *(const float4*)ap;
        a1 = *(const float4*)(ap + 4);
#pragma unroll
        for (int nb = 0; nb < 4; ++nb)
            b[0][nb] = *(const short8*)&Wf1[(((w * 4 + nb) * 8 + 0) * 64 + lane) * 8];
    }
#pragma unroll
    for (int kb = 0; kb < 8; ++kb) {
        if (kb < 7) {
            const float* ap = &x[rowA * 256 + (kb + 1) * 32 + kg * 8];
            a0n = *(const float4*)ap;
            a1n = *(const float4*)(ap + 4);
#pragma unroll
            for (int nb = 0; nb < 4; ++nb)
                b[(kb + 1) & 1][nb] =
                    *(const short8*)&Wf1[(((w * 4 + nb) * 8 + kb + 1) * 64 + lane) * 8];
        }
        short8 af;
        af[0] = (short)f2bf(a0.x); af[1] = (short)f2bf(a0.y);
        af[2] = (short)f2bf(a0.z); af[3] = (short)f2bf(a0.w);
        af[4] = (short)f2bf(a1.x); af[5] = (short)f2bf(a1.y);
        af[6] = (short)f2bf(a1.z); af[7] = (short)f2bf(a1.w);
#pragma unroll
        for (int nb = 0; nb < 4; ++nb)
            acc[nb] = __builtin_amdgcn_mfma_f32_16x16x32_bf16(af, b[kb & 1][nb], acc[nb], 0, 0, 0);
        if (kb < 7) { a0 = a0n; a1 = a1n; }
    }

#pragma unroll
    for (int reg = 0; reg < 4; ++reg) {
        int n = rbase + kg * 4 + reg;               // C/D row = kg*4+reg
#pragma unroll
        for (int nb = 0; nb < 4; ++nb)
            h1b[n * 256 + (w * 4 + nb) * 16 + q] = f2bf(acc[nb][reg]);
    }
    // fused attention dots for head w
    float asv[4], adv[4];
#pragma unroll
    for (int nb = 0; nb < 4; ++nb) {
        int col = (w * 4 + nb) * 16 + q;
        asv[nb] = att_src[col];
        adv[nb] = att_dst[col];
    }
#pragma unroll
    for (int reg = 0; reg < 4; ++reg) {
        float s = acc[0][reg]*asv[0] + acc[1][reg]*asv[1] + acc[2][reg]*asv[2] + acc[3][reg]*asv[3];
        float d = acc[0][reg]*adv[0] + acc[1][reg]*adv[1] + acc[2][reg]*adv[2] + acc[3][reg]*adv[3];
#pragma unroll
        for (int ofs = 1; ofs < 16; ofs <<= 1) {
            s += __shfl_xor(s, ofs);
            d += __shfl_xor(d, ofs);
        }
        if (q == 0) {
            int n = rbase + kg * 4 + reg;
            as1[n * 4 + w] = s;
            ad1[n * 4 + w] = d;
        }
    }
}

// ---------------------------------------------------------------------------
// alpha1: normalized softmax weights per edge, bf16, in CSR order.
// Wave per dst; lane = (edge slot, head). dn accumulated from the bf16-
// rounded weights so alphas sum to ~1 exactly.
// ---------------------------------------------------------------------------
__global__ __launch_bounds__(256) void k_alpha1(
    const int* __restrict__ esrc, const int* __restrict__ off,
    const float* __restrict__ as1, const float* __restrict__ ad1,
    unsigned short* __restrict__ aw1)
{
    int d    = (blockIdx.x * 256 + threadIdx.x) >> 6;
    int lane = threadIdx.x & 63;
    if (d >= N_NODES) return;
    const int head = lane & 3;
    const int ei   = lane >> 2;                     // 16 edge slots
    const float adv = ad1[d * 4 + head];
    const int e0 = off[d], e1 = off[d + 1];
    float dn = 0.f;
    for (int e = e0 + ei; e < e1; e += 16) {
        int s = esrc[e];
        float wv = __expf(lrelu(as1[s * 4 + head] + adv));
        unsigned short r = f2bf(wv);
        dn += bf2f(r);
        aw1[e * 4 + head] = r;
    }
#pragma unroll
    for (int ofs = 4; ofs < 64; ofs <<= 1) dn += __shfl_xor(dn, ofs);
    const float inv = 1.f / (dn + 1e-16f);
    for (int e = e0 + ei; e < e1; e += 16) {
        float wv = bf2f(aw1[e * 4 + head]);
        aw1[e * 4 + head] = f2bf(wv * inv);
    }
}

// ---------------------------------------------------------------------------
// gather1: column-partitioned weighted gather + bias + ELU.
// Grid 100000 = 12500 dst-chunks x 8 col-groups; cg = blockIdx%8 pins each
// 32-col slice (64 B/row, 3.2 MB total) to one XCD's L2 under round-robin
// dispatch (perf heuristic only). Wave per dst: lane = (col pair k, edge
// slot ep); 2x unroll -> 8 edges in flight; shfl_xor(16,32) reduce.
// ---------------------------------------------------------------------------
__global__ __launch_bounds__(256) void k_gather1(
    const int* __restrict__ esrc, const int* __restrict__ off,
    const unsigned short* __restrict__ aw1,
    const unsigned short* __restrict__ h1b, const float* __restrict__ b1,
    unsigned short* __restrict__ hmid)
{
    const int bid = blockIdx.x;
    const int cg  = bid & 7;
    const int t = threadIdx.x;
    const int w = t >> 6;
    const int lane = t & 63;
    const int d = (bid >> 3) * 4 + w;               // 12500*4 = 50000 exact
    const int k  = lane & 15;
    const int ep = lane >> 4;
    const int head = cg >> 1;
    const int e0 = off[d], e1 = off[d + 1];
    const unsigned short* hb = h1b + cg * 32 + k * 2;
    float a0 = 0.f, a1 = 0.f;
    int e = e0 + ep;
    for (; e + 4 < e1; e += 8) {
        int sA = esrc[e], sB = esrc[e + 4];
        float wA = bf2f(aw1[e * 4 + head]);
        float wB = bf2f(aw1[(e + 4) * 4 + head]);
        unsigned uA = *(const unsigned*)(hb + sA * 256);
        unsigned uB = *(const unsigned*)(hb + sB * 256);
        a0 = fmaf(wA, bf2f((unsigned short)uA), fmaf(wB, bf2f((unsigned short)uB), a0));
        a1 = fmaf(wA, bf2f((unsigned short)(uA >> 16)), fmaf(wB, bf2f((unsigned short)(uB >> 16)), a1));
    }
    if (e < e1) {
        int sA = esrc[e];
        float wA = bf2f(aw1[e * 4 + head]);
        unsigned uA = *(const unsigned*)(hb + sA * 256);
        a0 = fmaf(wA, bf2f((unsigned short)uA), a0);
        a1 = fmaf(wA, bf2f((unsigned short)(uA >> 16)), a1);
    }
    a0 += __shfl_xor(a0, 16); a0 += __shfl_xor(a0, 32);
    a1 += __shfl_xor(a1, 16); a1 += __shfl_xor(a1, 32);
    if (ep == 0) {
        int col = cg * 32 + k * 2;
        float v0 = a0 + b1[col];
        float v1 = a1 + b1[col + 1];
        v0 = v0 > 0.f ? v0 : expm1f(v0);
        v1 = v1 > 0.f ? v1 : expm1f(v1);
        unsigned pk = (unsigned)f2bf(v0) | ((unsigned)f2bf(v1) << 16);
        *(unsigned*)&hmid[d * 256 + col] = pk;
    }
}

// ---------------------------------------------------------------------------
// GEMM2: h2 = hmid @ W2. Plain layouts both sides; register double-buffer;
// fused att2 epilogue.
// ---------------------------------------------------------------------------
__global__ __launch_bounds__(256) void k_gemm2(
    const unsigned short* __restrict__ hmid, const unsigned short* __restrict__ Wf2,
    const float* __restrict__ att_src, const float* __restrict__ att_dst,
    unsigned short* __restrict__ h2b, float* __restrict__ as2, float* __restrict__ ad2)
{
    const int t = threadIdx.x;
    const int lane = t & 63;
    const int w = t >> 6;
    const int rbase = blockIdx.x * 64 + w * 16;
    const int q  = lane & 15;
    const int kg = lane >> 4;
    const int rowA = rbase + q;
    const int rA = rowA < N_NODES ? rowA : N_NODES - 1;

    f32x4 acc[4];
#pragma unroll
    for (int nb = 0; nb < 4; ++nb) acc[nb] = (f32x4){0.f, 0.f, 0.f, 0.f};

    short8 b[2][4];
    short8 af, afn;
    af = *(const short8*)&hmid[rA * 256 + kg * 8];
#pragma unroll
    for (int nb = 0; nb < 4; ++nb)
        b[0][nb] = *(const short8*)&Wf2[((nb * 8 + 0) * 64 + lane) * 8];
#pragma unroll
    for (int kb = 0; kb < 8; ++kb) {
        if (kb < 7) {
            afn = *(const short8*)&hmid[rA * 256 + (kb + 1) * 32 + kg * 8];
#pragma unroll
            for (int nb = 0; nb < 4; ++nb)
                b[(kb + 1) & 1][nb] = *(const short8*)&Wf2[((nb * 8 + kb + 1) * 64 + lane) * 8];
        }
#pragma unroll
        for (int nb = 0; nb < 4; ++nb)
            acc[nb] = __builtin_amdgcn_mfma_f32_16x16x32_bf16(af, b[kb & 1][nb], acc[nb], 0, 0, 0);
        if (kb < 7) af = afn;
    }

    float asv[4], adv[4];
#pragma unroll
    for (int nb = 0; nb < 4; ++nb) {
        int col = nb * 16 + q;
        asv[nb] = att_src[col];
        adv[nb] = att_dst[col];
    }
#pragma unroll
    for (int reg = 0; reg < 4; ++reg) {
        int n = rbase + kg * 4 + reg;
        bool ok = n < N_NODES;
        if (ok) {
#pragma unroll
            for (int nb = 0; nb < 4; ++nb)
                h2b[n * 64 + nb * 16 + q] = f2bf(acc[nb][reg]);
        }
        float s = acc[0][reg]*asv[0] + acc[1][reg]*asv[1] + acc[2][reg]*asv[2] + acc[3][reg]*asv[3];
        float d = acc[0][reg]*adv[0] + acc[1][reg]*adv[1] + acc[2][reg]*adv[2] + acc[3][reg]*adv[3];
#pragma unroll
        for (int ofs = 1; ofs < 16; ofs <<= 1) {
            s += __shfl_xor(s, ofs);
            d += __shfl_xor(d, ofs);
        }
        if (ok && q == 0) { as2[n] = s; ad2[n] = d; }
    }
}

// ---------------------------------------------------------------------------
// alpha2: normalized weights for layer 2 (1 head). Wave per dst, lane = edge.
// ---------------------------------------------------------------------------
__global__ __launch_bounds__(256) void k_alpha2(
    const int* __restrict__ esrc, const int* __restrict__ off,
    const float* __restrict__ as2, const float* __restrict__ ad2,
    unsigned short* __restrict__ aw2)
{
    int d    = (blockIdx.x * 256 + threadIdx.x) >> 6;
    int lane = threadIdx.x & 63;
    if (d >= N_NODES) return;
    const float adv = ad2[d];
    const int e0 = off[d], e1 = off[d + 1];
    float dn = 0.f;
    for (int e = e0 + lane; e < e1; e += 64) {
        int s = esrc[e];
        float wv = __expf(lrelu(as2[s] + adv));
        unsigned short r = f2bf(wv);
        dn += bf2f(r);
        aw2[e] = r;
    }
#pragma unroll
    for (int ofs = 1; ofs < 64; ofs <<= 1) dn += __shfl_xor(dn, ofs);
    const float inv = 1.f / (dn + 1e-16f);
    for (int e = e0 + lane; e < e1; e += 64) {
        aw2[e] = f2bf(bf2f(aw2[e]) * inv);
    }
}

// ---------------------------------------------------------------------------
// gather2: column-partitioned (2 groups of 32 cols; XCDs 0-3 -> cg0, 4-7 ->
// cg1, 1.6 MB slice per XCD-group L2). Writes d_out + bias.
// ---------------------------------------------------------------------------
__global__ __launch_bounds__(256) void k_gather2(
    const int* __restrict__ esrc, const int* __restrict__ off,
    const unsigned short* __restrict__ aw2,
    const unsigned short* __restrict__ h2b, const float* __restrict__ b2,
    float* __restrict__ out)
{
    const int bid = blockIdx.x;                     // 25000 blocks
    const int xcd = bid & 7;
    const int cg  = xcd >> 2;
    const int sub = xcd & 3;
    const int t = threadIdx.x;
    const int w = t >> 6;
    const int lane = t & 63;
    const int d = ((bid >> 3) * 4 + sub) * 4 + w;   // 3125*4*4 = 50000 exact
    const int k  = lane & 15;
    const int ep = lane >> 4;
    const int e0 = off[d], e1 = off[d + 1];
    const unsigned short* hb = h2b + cg * 32 + k * 2;
    float a0 = 0.f, a1 = 0.f;
    int e = e0 + ep;
    for (; e + 4 < e1; e += 8) {
        int sA = esrc[e], sB = esrc[e + 4];
        float wA = bf2f(aw2[e]);
        float wB = bf2f(aw2[e + 4]);
        unsigned uA = *(const unsigned*)(hb + sA * 64);
        unsigned uB = *(const unsigned*)(hb + sB * 64);
        a0 = fmaf(wA, bf2f((unsigned short)uA), fmaf(wB, bf2f((unsigned short)uB), a0));
        a1 = fmaf(wA, bf2f((unsigned short)(uA >> 16)), fmaf(wB, bf2f((unsigned short)(uB >> 16)), a1));
    }
    if (e < e1) {
        int sA = esrc[e];
        float wA = bf2f(aw2[e]);
        unsigned uA = *(const unsigned*)(hb + sA * 64);
        a0 = fmaf(wA, bf2f((unsigned short)uA), a0);
        a1 = fmaf(wA, bf2f((unsigned short)(uA >> 16)), a1);
    }
    a0 += __shfl_xor(a0, 16); a0 += __shfl_xor(a0, 32);
    a1 += __shfl_xor(a1, 16); a1 += __shfl_xor(a1, 32);
    if (ep == 0) {
        int col = cg * 32 + k * 2;
        float2 o;
        o.x = a0 + b2[col];
        o.y = a1 + b2[col + 1];
        *(float2*)&out[d * 64 + col] = o;
    }
}

// ---------------------------------------------------------------------------
// Workspace layout (bytes), total ~65.9 MB:
//   counts @ 0            200,000  [zeroed]
//   cursor @ 200,000      200,000  [zeroed]
//   off    @ 400,000      200,004
//   bsum   @ 600,064      800
//   as1    @ 600,896      800,000
//   ad1    @ 1,400,896    800,000
//   as2    @ 2,200,896    200,000
//   ad2    @ 2,400,896    200,000
//   esrc   @ 2,600,896    3,400,000
//   Wf1    @ 6,000,896    131,072
//   Wf2    @ 6,131,968    32,768
//   aw1    @ 6,164,736    6,800,000 bf16
//   aw2    @ 12,964,736   1,700,000 bf16
//   h1b    @ 14,664,736   25,600,000 bf16 plain (h2b reuses after gather1)
//   h2b    @ 14,664,736   6,400,000 bf16 plain
//   hmid   @ 40,264,736   25,600,000 bf16 plain
// ---------------------------------------------------------------------------
extern "C" void kernel_launch(void* const* d_in, const int* in_sizes, int n_in,
                              void* d_out, int out_size, void* d_ws, size_t ws_size,
                              hipStream_t stream)
{
    const float* x        = (const float*)d_in[0];
    const int*   ei       = (const int*)d_in[1];
    const float* W1       = (const float*)d_in[2];
    const float* att_src1 = (const float*)d_in[3];
    const float* att_dst1 = (const float*)d_in[4];
    const float* b1       = (const float*)d_in[5];
    const float* W2       = (const float*)d_in[6];
    const float* att_src2 = (const float*)d_in[7];
    const float* att_dst2 = (const float*)d_in[8];
    const float* b2       = (const float*)d_in[9];
    const int* src = ei;
    const int* dst = ei + E_RAW;
    float* out = (float*)d_out;

    char* ws = (char*)d_ws;
    int*            counts = (int*)(ws + 0);
    int*            cursor = (int*)(ws + 200000);
    int*            off    = (int*)(ws + 400000);
    int*            bsum   = (int*)(ws + 600064);
    float*          as1    = (float*)(ws + 600896);
    float*          ad1    = (float*)(ws + 1400896);
    float*          as2    = (float*)(ws + 2200896);
    float*          ad2    = (float*)(ws + 2400896);
    int*            esrc   = (int*)(ws + 2600896);
    unsigned short* Wf1    = (unsigned short*)(ws + 6000896);
    unsigned short* Wf2    = (unsigned short*)(ws + 6131968);
    unsigned short* aw1    = (unsigned short*)(ws + 6164736);
    unsigned short* aw2    = (unsigned short*)(ws + 12964736);
    unsigned short* h1b    = (unsigned short*)(ws + 14664736);
    unsigned short* h2b    = (unsigned short*)(ws + 14664736);  // reuses h1b
    unsigned short* hmid   = (unsigned short*)(ws + 40264736);

    hipMemsetAsync(ws, 0, 400000, stream);      // counts + cursor

    const int EB = (E_TOT + 255) / 256;
    k_prepw1 <<<32, 256, 0, stream>>>(W1, Wf1);
    k_prepw2 <<<8, 256, 0, stream>>>(W2, Wf2);
    k_hist   <<<EB, 256, 0, stream>>>(dst, counts);
    k_scan1  <<<NBC, 256, 0, stream>>>(counts, off, bsum);
    k_scan2  <<<1, 256, 0, stream>>>(bsum);
    k_scan3  <<<NBC, 256, 0, stream>>>(off, bsum);
    k_scatter<<<EB, 256, 0, stream>>>(src, dst, off, cursor, esrc);

    k_gemm1  <<<3125, 256, 0, stream>>>(x, Wf1, att_src1, att_dst1, h1b, as1, ad1);
    k_alpha1 <<<12500, 256, 0, stream>>>(esrc, off, as1, ad1, aw1);
    k_gather1<<<100000, 256, 0, stream>>>(esrc, off, aw1, h1b, b1, hmid);
    k_gemm2  <<<782, 256, 0, stream>>>(hmid, Wf2, att_src2, att_dst2, h2b, as2, ad2);
    k_alpha2 <<<12500, 256, 0, stream>>>(esrc, off, as2, ad2, aw2);
    k_gather2<<<25000, 256, 0, stream>>>(esrc, off, aw2, h2b, b2, out);
}